// Round 5
// baseline (1232.184 us; speedup 1.0000x reference)
//
#include <hip/hip_runtime.h>

// Problem constants (fixed by setup_inputs)
static constexpr int NN   = 100000;    // nodes
static constexpr int EE   = 2560000;   // edges
static constexpr int RR   = 8;         // relations
static constexpr int BB   = 8;         // bases
static constexpr int EPER = EE / RR;   // 320000 edges per relation

// Bucketed CSR build: bucket = dst >> 8 (256 nodes per bucket)
static constexpr int NB      = (NN + 255) / 256;   // 391 buckets
static constexpr int CHUNK_E = 8192;               // edges per block in hist/fill
static constexpr int EB      = (EE + CHUNK_E - 1) / CHUNK_E;  // 313 blocks

// Fused kernel geometry
static constexpr int WIN = 64;     // nodes per block
static constexpr int AST = 257;    // agg LDS row stride in floats (bank-friendly)

// payload packing: (d&255)<<23 | t<<20 | src   (src < 2^17 fits easily)

// ---------------------------------------------------------------------------
// K0: w[r][i][o] = sum_b att[r][b] * basis[b][i][o]   for both layers
// ---------------------------------------------------------------------------
__global__ __launch_bounds__(1024) void compute_w_kernel(
    const float* __restrict__ basis0, const float* __restrict__ att0,
    const float* __restrict__ basis1, const float* __restrict__ att1,
    float* __restrict__ w0, float* __restrict__ w1)
{
    const int r = blockIdx.x & 7;
    const bool l0 = blockIdx.x < 8;
    const float* basis = l0 ? basis0 : basis1;
    const float* att   = l0 ? att0   : att1;
    float*       w     = l0 ? w0     : w1;
    const int io = threadIdx.x;           // i*32 + o, 0..1023
    float acc = 0.f;
#pragma unroll
    for (int b = 0; b < BB; ++b)
        acc += att[r * BB + b] * basis[b * 1024 + io];
    w[r * 1024 + io] = acc;
}

// ---------------------------------------------------------------------------
// CSR build (two-level bucket sort, no per-edge global atomics)
// ---------------------------------------------------------------------------
__global__ __launch_bounds__(256) void bucket_hist_kernel(
    const int* __restrict__ dst, int* __restrict__ bucket_cnt)
{
    __shared__ int h[NB];
    for (int i = threadIdx.x; i < NB; i += 256) h[i] = 0;
    __syncthreads();
    const int base = blockIdx.x * CHUNK_E;
    for (int k = threadIdx.x; k < CHUNK_E; k += 256) {
        const int e = base + k;
        if (e < EE) atomicAdd(&h[dst[e] >> 8], 1);
    }
    __syncthreads();
    for (int i = threadIdx.x; i < NB; i += 256)
        if (h[i]) atomicAdd(&bucket_cnt[i], h[i]);
}

__global__ __launch_bounds__(512) void bucket_scan_kernel(
    const int* __restrict__ bucket_cnt, int* __restrict__ edge_base,
    int* __restrict__ cursor)
{
    __shared__ int s[512];
    const int v = (threadIdx.x < NB) ? bucket_cnt[threadIdx.x] : 0;
    s[threadIdx.x] = v;
    __syncthreads();
    for (int off = 1; off < 512; off <<= 1) {
        const int t = (threadIdx.x >= off) ? s[threadIdx.x - off] : 0;
        __syncthreads();
        s[threadIdx.x] += t;
        __syncthreads();
    }
    if (threadIdx.x < NB) {
        const int ex = s[threadIdx.x] - v;
        edge_base[threadIdx.x] = ex;
        cursor[threadIdx.x]    = ex;
    }
    if (threadIdx.x == NB) edge_base[NB] = EE;
}

// PassA: local hist -> one cursor reservation per (block,bucket) -> write
// contiguous runs of packed ints into the bucket regions.
__global__ __launch_bounds__(256) void bucket_fill_kernel(
    const int* __restrict__ src, const int* __restrict__ dst,
    int* __restrict__ cursor, int* __restrict__ pairs)
{
    __shared__ int h[NB];
    __shared__ int base_s[NB];
    for (int i = threadIdx.x; i < NB; i += 256) h[i] = 0;
    __syncthreads();
    const int base = blockIdx.x * CHUNK_E;
    for (int k = threadIdx.x; k < CHUNK_E; k += 256) {
        const int e = base + k;
        if (e < EE) atomicAdd(&h[dst[e] >> 8], 1);
    }
    __syncthreads();
    for (int i = threadIdx.x; i < NB; i += 256) {
        const int c = h[i];
        base_s[i] = c ? atomicAdd(&cursor[i], c) : 0;
    }
    __syncthreads();
    for (int i = threadIdx.x; i < NB; i += 256) h[i] = 0;
    __syncthreads();
    for (int k = threadIdx.x; k < CHUNK_E; k += 256) {
        const int e = base + k;
        if (e >= EE) continue;
        const int d = dst[e];
        const int b = d >> 8;
        const int pos = base_s[b] + atomicAdd(&h[b], 1);   // LDS atomic only
        const int t = e / EPER;     // edges sorted by type, equal blocks
        pairs[pos] = ((d & 255) << 23) | (t << 20) | src[e];
    }
}

// PassB: one block per bucket (256 nodes). LDS hist + scan -> row_start,
// then LDS-rank scatter of packed payload within the bucket's window.
__global__ __launch_bounds__(256) void bucket_sort_kernel(
    const int* __restrict__ pairs, const int* __restrict__ edge_base,
    int* __restrict__ row_start, int* __restrict__ payload)
{
    __shared__ int cnt_s[256];
    __shared__ int s[256];
    __shared__ int rs_s[256];
    const int b  = blockIdx.x;
    const int e0 = edge_base[b];
    const int e1 = edge_base[b + 1];

    cnt_s[threadIdx.x] = 0;
    __syncthreads();
    for (int k = e0 + threadIdx.x; k < e1; k += 256)
        atomicAdd(&cnt_s[(unsigned)pairs[k] >> 23], 1);
    __syncthreads();

    const int v = cnt_s[threadIdx.x];
    s[threadIdx.x] = v;
    __syncthreads();
    for (int off = 1; off < 256; off <<= 1) {
        const int t = (threadIdx.x >= off) ? s[threadIdx.x - off] : 0;
        __syncthreads();
        s[threadIdx.x] += t;
        __syncthreads();
    }
    rs_s[threadIdx.x] = s[threadIdx.x] - v;     // exclusive, bucket-relative

    const int n = (b << 8) + threadIdx.x;
    if (n <= NN) row_start[n] = e0 + rs_s[threadIdx.x];

    __syncthreads();
    cnt_s[threadIdx.x] = 0;                     // reuse as rank
    __syncthreads();
    for (int k = e0 + threadIdx.x; k < e1; k += 256) {
        const int p = pairs[k];
        const int loc = (unsigned)p >> 23;
        const int pos = e0 + rs_s[loc] + atomicAdd(&cnt_s[loc], 1);
        payload[pos] = p;
    }
}

// ---------------------------------------------------------------------------
// Fused RGCN layer: per 64-node window,
//   Phase A: edge aggregation into LDS agg[64][8*32] (8 edges per wave-inst,
//            lane=(edge,dim), runtime relation t is just an LDS address).
//   Phase B: dense transform agg@W with wave-uniform s_load weights; wave w
//            owns output dims [8w,8w+8) for all 64 nodes (no reduction).
//   Fused mean + relu + output-slice writes (+ x copy on layer 0).
// ---------------------------------------------------------------------------
__global__ __launch_bounds__(256) void rgcn_fused_kernel(
    const float* __restrict__ feat, const int* __restrict__ row_start,
    const int* __restrict__ payload, const float* __restrict__ w,
    const float* __restrict__ x, float* __restrict__ h_out,
    float* __restrict__ out, int col_off, int copy_x)
{
    __shared__ float agg[WIN * AST];
    const int tid = threadIdx.x;
    const int n0  = blockIdx.x * WIN;
    const int nw  = (NN - n0 < WIN) ? (NN - n0) : WIN;

    for (int i = tid; i < WIN * AST; i += 256) agg[i] = 0.f;
    __syncthreads();

    const int e_lo = row_start[n0];
    const int e_hi = row_start[n0 + nw];
    const int wofs = n0 & 255;
    const int li   = tid & 31;
    const int grp  = tid >> 5;

    for (int e = e_lo + grp; e < e_hi; e += 8) {
        const int p  = payload[e];
        const int dl = (int)((unsigned)p >> 23) - wofs;   // 0..WIN-1
        const int t  = (p >> 20) & 7;
        const int s  = p & 0xFFFFF;
        const float xv = feat[(size_t)s * 32 + li];
        atomicAdd(&agg[dl * AST + t * 32 + li], xv);
    }
    __syncthreads();

    // ---- transform ----
    const int wv = tid >> 6;        // wave 0..3 -> out dims [8wv, 8wv+8)
    const int nl = tid & 63;        // node lane
    if (nl >= nw) return;
    const int nn = n0 + nl;

    float acc[8];
#pragma unroll
    for (int o = 0; o < 8; ++o) acc[o] = 0.f;

    const float* aggp = &agg[nl * AST];
#pragma unroll
    for (int tt = 0; tt < 8; ++tt) {
        const float* wr = w + tt * 1024 + wv * 8;   // wave-uniform base
#pragma unroll
        for (int i = 0; i < 32; ++i) {
            const float av = aggp[tt * 32 + i];     // ds_read_b32, 2-way banks
#pragma unroll
            for (int o = 0; o < 8; ++o)
                acc[o] += av * wr[i * 32 + o];      // s_load weights
        }
    }

    const float deg = fmaxf((float)(row_start[nn + 1] - row_start[nn]), 1.f);
    const float inv = 1.0f / deg;
    float r[8];
#pragma unroll
    for (int o = 0; o < 8; ++o) r[o] = fmaxf(acc[o] * inv, 0.f);

    const float4 v0 = make_float4(r[0], r[1], r[2], r[3]);
    const float4 v1 = make_float4(r[4], r[5], r[6], r[7]);

    if (h_out) {
        float4* hp = reinterpret_cast<float4*>(h_out + (size_t)nn * 32 + wv * 8);
        hp[0] = v0; hp[1] = v1;
    }
    float4* op = reinterpret_cast<float4*>(out + (size_t)nn * 96 + col_off + wv * 8);
    op[0] = v0; op[1] = v1;

    if (copy_x) {
        const float4* xp = reinterpret_cast<const float4*>(x + (size_t)nn * 32 + wv * 8);
        float4* oxp = reinterpret_cast<float4*>(out + (size_t)nn * 96 + wv * 8);
        oxp[0] = xp[0]; oxp[1] = xp[1];
    }
}

// ---------------------------------------------------------------------------
extern "C" void kernel_launch(void* const* d_in, const int* in_sizes, int n_in,
                              void* d_out, int out_size, void* d_ws, size_t ws_size,
                              hipStream_t stream)
{
    const float* x      = (const float*)d_in[0];
    const int*   ei     = (const int*)d_in[1];
    const float* basis0 = (const float*)d_in[4];
    const float* att0   = (const float*)d_in[5];
    const float* basis1 = (const float*)d_in[6];
    const float* att1   = (const float*)d_in[7];
    const int* src = ei;
    const int* dst = ei + EE;
    float* out = (float*)d_out;
    float* ws  = (float*)d_ws;

    // ---- ws layout (4B units) ----
    float* w0         = ws;                                  // 8192
    float* w1         = w0 + 8192;                           // 8192
    int*   row_start  = (int*)(w1 + 8192);                   // NN+1
    int*   bucket_cnt = row_start + NN + 2;                  // NB
    int*   edge_base  = bucket_cnt + NB + 1;                 // NB+1
    int*   cursor     = edge_base + NB + 2;                  // NB
    int*   pairs      = cursor + NB + 1;                     // EE
    int*   payload    = pairs + EE;                          // EE
    float* h1         = (float*)(payload + EE);              // NN*32

    const int fuse_blocks = (NN + WIN - 1) / WIN;            // 1563

    compute_w_kernel<<<16, 1024, 0, stream>>>(basis0, att0, basis1, att1, w0, w1);

    // ---- CSR build (once, reused by both layers) ----
    hipMemsetAsync(bucket_cnt, 0, (size_t)NB * 4, stream);
    bucket_hist_kernel<<<EB, 256, 0, stream>>>(dst, bucket_cnt);
    bucket_scan_kernel<<<1, 512, 0, stream>>>(bucket_cnt, edge_base, cursor);
    bucket_fill_kernel<<<EB, 256, 0, stream>>>(src, dst, cursor, pairs);
    bucket_sort_kernel<<<NB, 256, 0, stream>>>(pairs, edge_base, row_start, payload);

    // ---- layer 0 ----
    rgcn_fused_kernel<<<fuse_blocks, 256, 0, stream>>>(
        x, row_start, payload, w0, x, h1, out, 32, 1);

    // ---- layer 1 ----
    rgcn_fused_kernel<<<fuse_blocks, 256, 0, stream>>>(
        h1, row_start, payload, w1, x, nullptr, out, 64, 0);
}

// Round 6
// 993.930 us; speedup vs baseline: 1.2397x; 1.2397x over previous
//
#include <hip/hip_runtime.h>

// Problem constants (fixed by setup_inputs)
static constexpr int NN   = 100000;    // nodes
static constexpr int EE   = 2560000;   // edges
static constexpr int RR   = 8;         // relations
static constexpr int BB   = 8;         // bases
static constexpr int EPER = EE / RR;   // 320000 edges per relation

// Bucketed CSR build: bucket = dst >> 8 (256 nodes per bucket)
static constexpr int NB      = (NN + 255) / 256;   // 391 buckets
static constexpr int CHUNK_E = 8192;               // edges per block in hist/fill
static constexpr int EB      = (EE + CHUNK_E - 1) / CHUNK_E;  // 313 blocks
static constexpr int NBIN    = 2048;               // (dst&255, t) bins per bucket

// Fused kernel geometry
static constexpr int WIN = 64;     // nodes per block
static constexpr int AST = 257;    // agg LDS row stride in floats (bank-friendly)

// pairs packing: (d&255)<<23 | t<<20 | src   (src < 2^17)
// payload after sort: src only (t implicit in [rs2[8n+t], rs2[8n+t+1]) ranges)

// ---------------------------------------------------------------------------
// K0: w[r][i][o] = sum_b att[r][b] * basis[b][i][o]   for both layers
// ---------------------------------------------------------------------------
__global__ __launch_bounds__(1024) void compute_w_kernel(
    const float* __restrict__ basis0, const float* __restrict__ att0,
    const float* __restrict__ basis1, const float* __restrict__ att1,
    float* __restrict__ w0, float* __restrict__ w1)
{
    const int r = blockIdx.x & 7;
    const bool l0 = blockIdx.x < 8;
    const float* basis = l0 ? basis0 : basis1;
    const float* att   = l0 ? att0   : att1;
    float*       w     = l0 ? w0     : w1;
    const int io = threadIdx.x;           // i*32 + o, 0..1023
    float acc = 0.f;
#pragma unroll
    for (int b = 0; b < BB; ++b)
        acc += att[r * BB + b] * basis[b * 1024 + io];
    w[r * 1024 + io] = acc;
}

// ---------------------------------------------------------------------------
// CSR build (two-level bucket sort, no per-edge global atomics)
// ---------------------------------------------------------------------------
__global__ __launch_bounds__(256) void bucket_hist_kernel(
    const int* __restrict__ dst, int* __restrict__ bucket_cnt)
{
    __shared__ int h[NB];
    for (int i = threadIdx.x; i < NB; i += 256) h[i] = 0;
    __syncthreads();
    const int base = blockIdx.x * CHUNK_E;
    for (int k = threadIdx.x; k < CHUNK_E; k += 256) {
        const int e = base + k;
        if (e < EE) atomicAdd(&h[dst[e] >> 8], 1);
    }
    __syncthreads();
    for (int i = threadIdx.x; i < NB; i += 256)
        if (h[i]) atomicAdd(&bucket_cnt[i], h[i]);
}

__global__ __launch_bounds__(512) void bucket_scan_kernel(
    const int* __restrict__ bucket_cnt, int* __restrict__ edge_base,
    int* __restrict__ cursor)
{
    __shared__ int s[512];
    const int v = (threadIdx.x < NB) ? bucket_cnt[threadIdx.x] : 0;
    s[threadIdx.x] = v;
    __syncthreads();
    for (int off = 1; off < 512; off <<= 1) {
        const int t = (threadIdx.x >= off) ? s[threadIdx.x - off] : 0;
        __syncthreads();
        s[threadIdx.x] += t;
        __syncthreads();
    }
    if (threadIdx.x < NB) {
        const int ex = s[threadIdx.x] - v;
        edge_base[threadIdx.x] = ex;
        cursor[threadIdx.x]    = ex;
    }
    if (threadIdx.x == NB) edge_base[NB] = EE;
}

// PassA: local hist -> one cursor reservation per (block,bucket) -> write
// contiguous runs of packed ints into the bucket regions.
__global__ __launch_bounds__(256) void bucket_fill_kernel(
    const int* __restrict__ src, const int* __restrict__ dst,
    int* __restrict__ cursor, int* __restrict__ pairs)
{
    __shared__ int h[NB];
    __shared__ int base_s[NB];
    for (int i = threadIdx.x; i < NB; i += 256) h[i] = 0;
    __syncthreads();
    const int base = blockIdx.x * CHUNK_E;
    for (int k = threadIdx.x; k < CHUNK_E; k += 256) {
        const int e = base + k;
        if (e < EE) atomicAdd(&h[dst[e] >> 8], 1);
    }
    __syncthreads();
    for (int i = threadIdx.x; i < NB; i += 256) {
        const int c = h[i];
        base_s[i] = c ? atomicAdd(&cursor[i], c) : 0;
    }
    __syncthreads();
    for (int i = threadIdx.x; i < NB; i += 256) h[i] = 0;
    __syncthreads();
    for (int k = threadIdx.x; k < CHUNK_E; k += 256) {
        const int e = base + k;
        if (e >= EE) continue;
        const int d = dst[e];
        const int b = d >> 8;
        const int pos = base_s[b] + atomicAdd(&h[b], 1);   // LDS atomic only
        const int t = e / EPER;     // edges sorted by type, equal blocks
        pairs[pos] = ((d & 255) << 23) | (t << 20) | src[e];
    }
}

// PassB: one block per bucket. 2048-bin ((dst&255)*8 | t) LDS hist + scan ->
// rs2[n*8+t] global boundaries, then LDS-rank scatter of src-only payload.
__global__ __launch_bounds__(256) void bucket_sort_kernel(
    const int* __restrict__ pairs, const int* __restrict__ edge_base,
    int* __restrict__ rs2, int* __restrict__ payload)
{
    __shared__ int cnt_s[NBIN];
    __shared__ int rs_s[NBIN];
    __shared__ int s[256];
    const int b  = blockIdx.x;
    const int e0 = edge_base[b];
    const int e1 = edge_base[b + 1];

    for (int i = threadIdx.x; i < NBIN; i += 256) cnt_s[i] = 0;
    __syncthreads();
    for (int k = e0 + threadIdx.x; k < e1; k += 256)
        atomicAdd(&cnt_s[(unsigned)pairs[k] >> 20], 1);
    __syncthreads();

    // scan 2048 bins: each thread owns 8 consecutive bins
    int loc[8];
    int tot = 0;
#pragma unroll
    for (int j = 0; j < 8; ++j) {
        loc[j] = tot;
        tot += cnt_s[threadIdx.x * 8 + j];
    }
    s[threadIdx.x] = tot;
    __syncthreads();
    for (int off = 1; off < 256; off <<= 1) {
        const int t = (threadIdx.x >= off) ? s[threadIdx.x - off] : 0;
        __syncthreads();
        s[threadIdx.x] += t;
        __syncthreads();
    }
    const int base_ex = s[threadIdx.x] - tot;   // exclusive block prefix
#pragma unroll
    for (int j = 0; j < 8; ++j)
        rs_s[threadIdx.x * 8 + j] = base_ex + loc[j];
    __syncthreads();

    // rs2[b*2048 + bin] = e0 + rs  ->  rs2[n*8+t] globally
    for (int i = threadIdx.x; i < NBIN; i += 256)
        rs2[b * NBIN + i] = e0 + rs_s[i];

    // scatter: payload = src only, sorted by (dst, t)
    for (int i = threadIdx.x; i < NBIN; i += 256) cnt_s[i] = 0;
    __syncthreads();
    for (int k = e0 + threadIdx.x; k < e1; k += 256) {
        const int p = pairs[k];
        const int l = (unsigned)p >> 20;
        const int pos = e0 + rs_s[l] + atomicAdd(&cnt_s[l], 1);
        payload[pos] = p & 0xFFFFF;
    }
}

// ---------------------------------------------------------------------------
// Fused RGCN layer, atomic-free:
//   Edge phase: 8 groups of 32 lanes (lane = dim); group owns 8 consecutive
//     nodes sequentially. Per node: chunk-load 32 payloads (coalesced),
//     8 static-t sub-loops over [rs2[8n+t], rs2[8n+t+1]) accumulate into
//     registers a0..a7 (feat rows are 128B coalesced, L2/L3-hot), then
//     8 ds_writes into the agg tile. No atomics anywhere.
//   Transform: thread = (node, 8-dim slice); weights via wave-uniform s_load;
//     fused mean + relu + output writes (+ x copy on layer 0).
// ---------------------------------------------------------------------------
__global__ __launch_bounds__(256) void rgcn_fused_kernel(
    const float* __restrict__ feat, const int* __restrict__ rs2,
    const int* __restrict__ payload, const float* __restrict__ w,
    const float* __restrict__ x, float* __restrict__ h_out,
    float* __restrict__ out, int col_off, int copy_x)
{
    __shared__ float agg[WIN * AST];
    __shared__ float deg_s[WIN];
    const int tid = threadIdx.x;
    const int n0  = blockIdx.x * WIN;
    const int li  = tid & 31;
    const int g   = tid >> 5;

    // ---- edge phase ----
    for (int j = 0; j < 8; ++j) {
        const int nn = n0 + g * 8 + j;
        if (nn >= NN) break;                       // uniform per group
        const int bq = rs2[nn * 8 + ((li <= 8) ? li : 8)];
        const int b0 = __shfl(bq, 0, 32), b1 = __shfl(bq, 1, 32);
        const int b2 = __shfl(bq, 2, 32), b3 = __shfl(bq, 3, 32);
        const int b4 = __shfl(bq, 4, 32), b5 = __shfl(bq, 5, 32);
        const int b6 = __shfl(bq, 6, 32), b7 = __shfl(bq, 7, 32);
        const int b8 = __shfl(bq, 8, 32);

        float a0 = 0.f, a1 = 0.f, a2 = 0.f, a3 = 0.f;
        float a4 = 0.f, a5 = 0.f, a6 = 0.f, a7 = 0.f;

        for (int eb = b0; eb < b8; eb += 32) {
            const int nloc = min(32, b8 - eb);
            const int p = (li < nloc) ? payload[eb + li] : 0;
#define SUBLOOP(LO, HI, ACC)                                                   \
            {                                                                  \
                const int lo = (LO > eb) ? LO : eb;                            \
                const int hi = (HI < eb + nloc) ? HI : eb + nloc;              \
                for (int k = lo; k < hi; ++k) {                                \
                    const int sID = __shfl(p, k - eb, 32);                     \
                    ACC += feat[(size_t)sID * 32 + li];                        \
                }                                                              \
            }
            SUBLOOP(b0, b1, a0)
            SUBLOOP(b1, b2, a1)
            SUBLOOP(b2, b3, a2)
            SUBLOOP(b3, b4, a3)
            SUBLOOP(b4, b5, a4)
            SUBLOOP(b5, b6, a5)
            SUBLOOP(b6, b7, a6)
            SUBLOOP(b7, b8, a7)
#undef SUBLOOP
        }

        const int nl = g * 8 + j;
        float* ap = &agg[nl * AST + li];
        ap[0]   = a0; ap[32]  = a1; ap[64]  = a2; ap[96]  = a3;
        ap[128] = a4; ap[160] = a5; ap[192] = a6; ap[224] = a7;
        if (li == 0) deg_s[nl] = (float)(b8 - b0);
    }
    __syncthreads();

    // ---- transform ----
    const int wv = tid >> 6;        // wave -> out dims [8wv, 8wv+8)
    const int nl = tid & 63;
    const int nn = n0 + nl;
    if (nn >= NN) return;

    float acc[8];
#pragma unroll
    for (int o = 0; o < 8; ++o) acc[o] = 0.f;

    const float* aggp = &agg[nl * AST];
#pragma unroll
    for (int tt = 0; tt < 8; ++tt) {
        const float* wr = w + tt * 1024 + wv * 8;   // wave-uniform base
#pragma unroll
        for (int i = 0; i < 32; ++i) {
            const float av = aggp[tt * 32 + i];
#pragma unroll
            for (int o = 0; o < 8; ++o)
                acc[o] += av * wr[i * 32 + o];      // s_load weights
        }
    }

    const float inv = 1.0f / fmaxf(deg_s[nl], 1.0f);
    float r[8];
#pragma unroll
    for (int o = 0; o < 8; ++o) r[o] = fmaxf(acc[o] * inv, 0.f);

    const float4 v0 = make_float4(r[0], r[1], r[2], r[3]);
    const float4 v1 = make_float4(r[4], r[5], r[6], r[7]);

    if (h_out) {
        float4* hp = reinterpret_cast<float4*>(h_out + (size_t)nn * 32 + wv * 8);
        hp[0] = v0; hp[1] = v1;
    }
    float4* op = reinterpret_cast<float4*>(out + (size_t)nn * 96 + col_off + wv * 8);
    op[0] = v0; op[1] = v1;

    if (copy_x) {
        const float4* xp = reinterpret_cast<const float4*>(x + (size_t)nn * 32 + wv * 8);
        float4* oxp = reinterpret_cast<float4*>(out + (size_t)nn * 96 + wv * 8);
        oxp[0] = xp[0]; oxp[1] = xp[1];
    }
}

// ---------------------------------------------------------------------------
extern "C" void kernel_launch(void* const* d_in, const int* in_sizes, int n_in,
                              void* d_out, int out_size, void* d_ws, size_t ws_size,
                              hipStream_t stream)
{
    const float* x      = (const float*)d_in[0];
    const int*   ei     = (const int*)d_in[1];
    const float* basis0 = (const float*)d_in[4];
    const float* att0   = (const float*)d_in[5];
    const float* basis1 = (const float*)d_in[6];
    const float* att1   = (const float*)d_in[7];
    const int* src = ei;
    const int* dst = ei + EE;
    float* out = (float*)d_out;
    float* ws  = (float*)d_ws;

    // ---- ws layout (4B units) ----
    float* w0         = ws;                                  // 8192
    float* w1         = w0 + 8192;                           // 8192
    int*   rs2        = (int*)(w1 + 8192);                   // NB*NBIN + 8
    int*   bucket_cnt = rs2 + NB * NBIN + 8;                 // NB
    int*   edge_base  = bucket_cnt + NB + 1;                 // NB+1
    int*   cursor     = edge_base + NB + 2;                  // NB
    int*   pairs      = cursor + NB + 1;                     // EE
    int*   payload    = pairs + EE;                          // EE
    float* h1         = (float*)(payload + EE);              // NN*32

    const int fuse_blocks = (NN + WIN - 1) / WIN;            // 1563

    compute_w_kernel<<<16, 1024, 0, stream>>>(basis0, att0, basis1, att1, w0, w1);

    // ---- CSR build (once, reused by both layers) ----
    hipMemsetAsync(bucket_cnt, 0, (size_t)NB * 4, stream);
    bucket_hist_kernel<<<EB, 256, 0, stream>>>(dst, bucket_cnt);
    bucket_scan_kernel<<<1, 512, 0, stream>>>(bucket_cnt, edge_base, cursor);
    bucket_fill_kernel<<<EB, 256, 0, stream>>>(src, dst, cursor, pairs);
    bucket_sort_kernel<<<NB, 256, 0, stream>>>(pairs, edge_base, rs2, payload);

    // ---- layer 0 ----
    rgcn_fused_kernel<<<fuse_blocks, 256, 0, stream>>>(
        x, rs2, payload, w0, x, h1, out, 32, 1);

    // ---- layer 1 ----
    rgcn_fused_kernel<<<fuse_blocks, 256, 0, stream>>>(
        h1, rs2, payload, w1, x, nullptr, out, 64, 0);
}